// Round 8
// baseline (398.447 us; speedup 1.0000x reference)
//
#include <hip/hip_runtime.h>
#include <hip/hip_bf16.h>
#include <stdint.h>

#define F_IN 512
#define HID 32
#define HEADS 8
#define C1 (HEADS*HID)   // 256
#define CLS 64
#define NEG 0.2f
#define EPS 1e-16f

typedef __bf16 bf16x8 __attribute__((ext_vector_type(8)));
typedef __bf16 bf16x4 __attribute__((ext_vector_type(4)));
typedef float  f32x4  __attribute__((ext_vector_type(4)));

__device__ __forceinline__ float leaky(float v) { return v > 0.f ? v : NEG * v; }

__device__ __forceinline__ bf16x8 cvt8(float4 a, float4 b) {
  bf16x8 o;
  o[0] = (__bf16)a.x; o[1] = (__bf16)a.y; o[2] = (__bf16)a.z; o[3] = (__bf16)a.w;
  o[4] = (__bf16)b.x; o[5] = (__bf16)b.y; o[6] = (__bf16)b.z; o[7] = (__bf16)b.w;
  return o;
}

// async global->LDS, 16B per lane (dest is wave-uniform base + lane*16: layouts linear in tid)
#define GLOAD_LDS16(gsrc, ldst) \
  __builtin_amdgcn_global_load_lds((const __attribute__((address_space(1))) void*)(gsrc), \
      (__attribute__((address_space(3))) void*)(ldst), 16, 0, 0)

// ---------------- fused prep: cvt_w1t | cvt_w2t | count_deg ----------------
__global__ __launch_bounds__(256) void prep(const float* __restrict__ W1,
    const float* __restrict__ W2, const int* __restrict__ ei,
    __bf16* __restrict__ w1t, __bf16* __restrict__ w2t,
    int* __restrict__ deg, int E) {
  const int b = blockIdx.x, t = threadIdx.x;
  if (b < 64) {
    int i = b * 256 + t;
    int o0 = i * 8;
    int c = o0 >> 9, k0 = o0 & 511;
    bf16x8 o;
#pragma unroll
    for (int j = 0; j < 8; j++) o[j] = (__bf16)W1[(size_t)(k0 + j) * C1 + c];
    *(bf16x8*)(w1t + (size_t)o0) = o;
  } else if (b < 72) {
    int i = (b - 64) * 256 + t;
    int o0 = i * 8;
    int c = o0 >> 8, k0 = o0 & 255;
    bf16x8 o;
#pragma unroll
    for (int j = 0; j < 8; j++) o[j] = (__bf16)W2[(size_t)(k0 + j) * CLS + c];
    *(bf16x8*)(w2t + (size_t)o0) = o;
  } else {
    int e = (b - 72) * 256 + t;
    if (e < E) atomicAdd(&deg[ei[E + e]], 1);
  }
}

// ---------------- parallel exclusive scan ----------------
__global__ __launch_bounds__(256) void scan_k1(const int* __restrict__ deg,
    int* __restrict__ bsum, int N) {
  __shared__ int ws[4];
  const int t = threadIdx.x, lane = t & 63, wid = t >> 6;
  int i = blockIdx.x * 256 + t;
  int v = (i < N) ? deg[i] : 0;
#pragma unroll
  for (int o = 1; o < 64; o <<= 1) v += __shfl_xor(v, o);
  if (lane == 0) ws[wid] = v;
  __syncthreads();
  if (t == 0) bsum[blockIdx.x] = ws[0] + ws[1] + ws[2] + ws[3];
}

__global__ __launch_bounds__(256) void scan_k2(int* __restrict__ bsum, int nb) {
  __shared__ int wsum[4];
  __shared__ int carry_s;
  const int t = threadIdx.x, lane = t & 63, wid = t >> 6;
  if (t == 0) carry_s = 0;
  __syncthreads();
  for (int base = 0; base < nb; base += 256) {
    int i = base + t;
    int v = (i < nb) ? bsum[i] : 0;
    int inc = v;
#pragma unroll
    for (int o = 1; o < 64; o <<= 1) { int x = __shfl_up(inc, o); if (lane >= o) inc += x; }
    if (lane == 63) wsum[wid] = inc;
    __syncthreads();
    int woff = 0;
    for (int w = 0; w < wid; w++) woff += wsum[w];
    int excl = carry_s + woff + inc - v;
    if (i < nb) bsum[i] = excl;
    __syncthreads();
    if (t == 0) carry_s += wsum[0] + wsum[1] + wsum[2] + wsum[3];
    __syncthreads();
  }
}

__global__ __launch_bounds__(256) void scan_k3(const int* __restrict__ deg,
    const int* __restrict__ bsum, int* __restrict__ rowstart,
    int* __restrict__ cur, int N) {
  __shared__ int wsum[4];
  const int t = threadIdx.x, lane = t & 63, wid = t >> 6;
  int i = blockIdx.x * 256 + t;
  int v = (i < N) ? deg[i] : 0;
  int inc = v;
#pragma unroll
  for (int o = 1; o < 64; o <<= 1) { int x = __shfl_up(inc, o); if (lane >= o) inc += x; }
  if (lane == 63) wsum[wid] = inc;
  __syncthreads();
  int woff = 0;
  for (int w = 0; w < wid; w++) woff += wsum[w];
  int excl = bsum[blockIdx.x] + woff + inc - v;
  if (i < N) { rowstart[i] = excl; cur[i] = excl; }
  if (i == N - 1) rowstart[N] = excl + v;
}

__global__ __launch_bounds__(256) void scatter_csr(const int* __restrict__ ei,
    int* __restrict__ cur, int* __restrict__ csr_src, int E) {
  int e = blockIdx.x * 256 + threadIdx.x;
  if (e >= E) return;
  int s = ei[e], d = ei[E + e];
  int pos = atomicAdd(&cur[d], 1);
  csr_src[pos] = s;
}

// ---------------- GEMM1 fused: h1 = x @ w1t^T, BM=128 x BN=256, 8 waves ----------------
// A (fp32 x) staged once per block via regs+cvt; B (bf16) staged via global_load_lds into
// a double-buffered LDS region (issue B(kk+1) after mid-barrier -> latency spans MFMA phase).
__global__ __launch_bounds__(512) void gemm1_fused(const float* __restrict__ A,
    const __bf16* __restrict__ Bt, __bf16* __restrict__ C,
    const float* __restrict__ asw, const float* __restrict__ adw,
    float* __restrict__ a_src, float* __restrict__ a_dst, int M) {
  __shared__ __bf16 Al[128 * 32];
  __shared__ __bf16 Bl[2][256 * 32];
  const int tid = threadIdx.x, lane = tid & 63, wave = tid >> 6;  // wave 0..7
  const int lm = lane & 15, q = lane >> 4;
  const int wr = ((wave >> 1) & 1) * 64;                 // row half: 0 or 64
  const int cb = (wave >> 2) * 128 + (wave & 1) * 64;    // col block: 0,64,128,192
  const int bm = blockIdx.x * 128;
  const int srow = tid >> 2, skc = (tid & 3) * 8;        // srow 0..127

  f32x4 acc[4][4];
#pragma unroll
  for (int i = 0; i < 4; i++)
#pragma unroll
    for (int j = 0; j < 4; j++) acc[i][j] = (f32x4){0.f, 0.f, 0.f, 0.f};

  const int ra = min(bm + srow, M - 1);

  const __bf16* gb0 = Bt + (size_t)srow * 512 + skc;          // rows 0..127
  const __bf16* gb1 = Bt + (size_t)(srow + 128) * 512 + skc;  // rows 128..255
  const int lb0 = srow * 32 + skc;            // elem == tid*8 (16B/lane, linear per wave)
  const int lb1 = (srow + 128) * 32 + skc;    // elem == 4096 + tid*8

  float4 a0, a1;
  a0  = *(const float4*)(A + (size_t)ra * 512 + skc);
  a1  = *(const float4*)(A + (size_t)ra * 512 + skc + 4);
  // prologue: B(0) -> buf0
  GLOAD_LDS16(gb0, &Bl[0][lb0]);
  GLOAD_LDS16(gb1, &Bl[0][lb1]);

  for (int kk = 0; kk < 16; kk++) {
    __syncthreads();   // prev-iter LDS readers done; drains B(kk) DMA + A(kk) reg loads
    *(bf16x8*)(Al + srow * 32 + skc) = cvt8(a0, a1);
    __syncthreads();   // A(kk) visible (B(kk) already drained above)
    if (kk + 1 < 16) {
      const int k0 = (kk + 1) * 32;
      GLOAD_LDS16(gb0 + k0, &Bl[(kk + 1) & 1][lb0]);
      GLOAD_LDS16(gb1 + k0, &Bl[(kk + 1) & 1][lb1]);
      a0 = *(const float4*)(A + (size_t)ra * 512 + k0 + skc);
      a1 = *(const float4*)(A + (size_t)ra * 512 + k0 + skc + 4);
    }
    bf16x8 af[4], bfr[4];
#pragma unroll
    for (int mi = 0; mi < 4; mi++)
      af[mi] = *(const bf16x8*)(Al + (wr + mi * 16 + lm) * 32 + q * 8);
#pragma unroll
    for (int ni = 0; ni < 4; ni++)
      bfr[ni] = *(const bf16x8*)(&Bl[kk & 1][(cb + ni * 16 + lm) * 32 + q * 8]);
#pragma unroll
    for (int mi = 0; mi < 4; mi++)
#pragma unroll
      for (int ni = 0; ni < 4; ni++)
        acc[mi][ni] = __builtin_amdgcn_mfma_f32_16x16x32_bf16(af[mi], bfr[ni], acc[mi][ni], 0, 0, 0);
  }

  // store h1 (bf16)
#pragma unroll
  for (int mi = 0; mi < 4; mi++) {
#pragma unroll
    for (int ni = 0; ni < 4; ni++) {
      const int col = cb + ni * 16 + lm;
#pragma unroll
      for (int r = 0; r < 4; r++) {
        const int row = bm + wr + mi * 16 + q * 4 + r;
        if (row < M) C[(size_t)row * C1 + col] = (__bf16)acc[mi][ni][r];
      }
    }
  }

  // fused scores from fp32 acc: this wave covers heads h0, h0+1 (cols cb .. cb+63)
  {
    const int h0 = cb >> 5;
    float ws[4], wd[4];
#pragma unroll
    for (int ni = 0; ni < 4; ni++) {
      ws[ni] = asw[cb + ni * 16 + lm];
      wd[ni] = adw[cb + ni * 16 + lm];
    }
#pragma unroll
    for (int mi = 0; mi < 4; mi++) {
#pragma unroll
      for (int r = 0; r < 4; r++) {
        float ps0 = acc[mi][0][r] * ws[0] + acc[mi][1][r] * ws[1];
        float ps1 = acc[mi][2][r] * ws[2] + acc[mi][3][r] * ws[3];
        float pd0 = acc[mi][0][r] * wd[0] + acc[mi][1][r] * wd[1];
        float pd1 = acc[mi][2][r] * wd[2] + acc[mi][3][r] * wd[3];
#pragma unroll
        for (int o = 1; o <= 8; o <<= 1) {
          ps0 += __shfl_xor(ps0, o); ps1 += __shfl_xor(ps1, o);
          pd0 += __shfl_xor(pd0, o); pd1 += __shfl_xor(pd1, o);
        }
        if (lm == 0) {
          const int row = bm + wr + mi * 16 + q * 4 + r;
          if (row < M) {
            a_src[(size_t)row * 8 + h0]     = ps0;
            a_src[(size_t)row * 8 + h0 + 1] = ps1;
            a_dst[(size_t)row * 8 + h0]     = pd0;
            a_dst[(size_t)row * 8 + h0 + 1] = pd1;
          }
        }
      }
    }
  }
}

// ---------------- GEMM2 fused: h2b = o1 @ w2t^T (bf16 out) + att scores 2 ----------------
__global__ __launch_bounds__(256) void gemm2_fused(const __bf16* __restrict__ A,
    const __bf16* __restrict__ Bt, __bf16* __restrict__ C,
    const float* __restrict__ asw, const float* __restrict__ adw,
    float* __restrict__ a_src, float* __restrict__ a_dst, int M) {
  __shared__ __bf16 Al[128 * 32];
  __shared__ __bf16 Bl[64 * 32];
  __shared__ float sred[128][2][2];
  const int tid = threadIdx.x, lane = tid & 63, wave = tid >> 6;
  const int lm = lane & 15, q = lane >> 4;
  const int wr = (wave >> 1) * 64, wc = (wave & 1) * 32;
  const int bm = blockIdx.x * 128;
  const int srow = tid >> 2, skc = (tid & 3) * 8;

  f32x4 acc[4][2];
#pragma unroll
  for (int i = 0; i < 4; i++)
#pragma unroll
    for (int j = 0; j < 2; j++) acc[i][j] = (f32x4){0.f, 0.f, 0.f, 0.f};

  const int ra0 = min(bm + srow, M - 1);
  const int ra1 = min(bm + srow + 64, M - 1);

  bf16x8 va0, va1, vb;
  va0 = *(const bf16x8*)(A + (size_t)ra0 * C1 + skc);
  va1 = *(const bf16x8*)(A + (size_t)ra1 * C1 + skc);
  vb  = *(const bf16x8*)(Bt + (size_t)srow * C1 + skc);

  for (int kk = 0; kk < 8; kk++) {
    __syncthreads();
    *(bf16x8*)(Al + srow * 32 + skc)        = va0;
    *(bf16x8*)(Al + (srow + 64) * 32 + skc) = va1;
    *(bf16x8*)(Bl + srow * 32 + skc)        = vb;
    __syncthreads();
    if (kk + 1 < 8) {
      const int k0 = (kk + 1) * 32;
      va0 = *(const bf16x8*)(A + (size_t)ra0 * C1 + k0 + skc);
      va1 = *(const bf16x8*)(A + (size_t)ra1 * C1 + k0 + skc);
      vb  = *(const bf16x8*)(Bt + (size_t)srow * C1 + k0 + skc);
    }
    bf16x8 af[4], bfr[2];
#pragma unroll
    for (int mi = 0; mi < 4; mi++)
      af[mi] = *(const bf16x8*)(Al + (wr + mi * 16 + lm) * 32 + q * 8);
#pragma unroll
    for (int ni = 0; ni < 2; ni++)
      bfr[ni] = *(const bf16x8*)(Bl + (wc + ni * 16 + lm) * 32 + q * 8);
#pragma unroll
    for (int mi = 0; mi < 4; mi++)
#pragma unroll
      for (int ni = 0; ni < 2; ni++)
        acc[mi][ni] = __builtin_amdgcn_mfma_f32_16x16x32_bf16(af[mi], bfr[ni], acc[mi][ni], 0, 0, 0);
  }

  float ws[2], wd[2];
#pragma unroll
  for (int ni = 0; ni < 2; ni++) {
    ws[ni] = asw[wc + ni * 16 + lm];
    wd[ni] = adw[wc + ni * 16 + lm];
  }
#pragma unroll
  for (int mi = 0; mi < 4; mi++) {
#pragma unroll
    for (int ni = 0; ni < 2; ni++) {
      const int col = wc + ni * 16 + lm;
#pragma unroll
      for (int r = 0; r < 4; r++) {
        const int row = bm + wr + mi * 16 + q * 4 + r;
        if (row < M) C[(size_t)row * CLS + col] = (__bf16)acc[mi][ni][r];
      }
    }
#pragma unroll
    for (int r = 0; r < 4; r++) {
      float ps = acc[mi][0][r] * ws[0] + acc[mi][1][r] * ws[1];
      float pd = acc[mi][0][r] * wd[0] + acc[mi][1][r] * wd[1];
#pragma unroll
      for (int o = 1; o <= 8; o <<= 1) { ps += __shfl_xor(ps, o); pd += __shfl_xor(pd, o); }
      if (lm == 0) {
        const int rl = wr + mi * 16 + q * 4 + r;
        sred[rl][wave & 1][0] = ps;
        sred[rl][wave & 1][1] = pd;
      }
    }
  }
  __syncthreads();
  if (tid < 128) {
    const int row = bm + tid;
    if (row < M) {
      a_src[row] = sred[tid][0][0] + sred[tid][1][0];
      a_dst[row] = sred[tid][0][1] + sred[tid][1][1];
    }
  }
}

// ---------------- layer-1 gather (r0-proven exact: ~76.7µs, VGPR 36, occ 61%) ----------------
__global__ __launch_bounds__(256) void gather1(const int* __restrict__ rowstart,
    const int* __restrict__ csr_src, const __bf16* __restrict__ h1,
    const float* __restrict__ as1, const float* __restrict__ ad1,
    const float* __restrict__ b1, __bf16* __restrict__ o1, int N) {
  const int t = threadIdx.x;
  const int d = blockIdx.x * 4 + (t >> 6);
  if (d >= N) return;
  const int lane = t & 63;
  const int e8 = lane >> 3, hh = lane & 7;
  const int r0 = rowstart[d];
  const int deg = rowstart[d + 1] - r0;

  const float addh = ad1[(size_t)d * 8 + hh];
  const float self_sc = leaky(as1[(size_t)d * 8 + hh] + addh);

  int   se[8];
  float sc[8];
#pragma unroll
  for (int ch = 0; ch < 8; ch++) {
    const int j = ch * 8 + e8;
    se[ch] = 0; sc[ch] = -3.4e38f;
    if (j < deg) {
      int s = csr_src[r0 + j];
      se[ch] = s;
      sc[ch] = leaky(as1[(size_t)s * 8 + hh] + addh);
    }
  }
  float mx = -3.4e38f;
#pragma unroll
  for (int ch = 0; ch < 8; ch++) mx = fmaxf(mx, sc[ch]);
  for (int j0 = 64; j0 < deg; j0 += 8) {
    int j = j0 + e8;
    if (j < deg) {
      int s = csr_src[r0 + j];
      mx = fmaxf(mx, leaky(as1[(size_t)s * 8 + hh] + addh));
    }
  }
  mx = fmaxf(mx, __shfl_xor(mx, 8));
  mx = fmaxf(mx, __shfl_xor(mx, 16));
  mx = fmaxf(mx, __shfl_xor(mx, 32));
  mx = fmaxf(mx, self_sc);

  float sum = 0.f;
#pragma unroll
  for (int ch = 0; ch < 8; ch++)
    if (ch * 8 + e8 < deg) sum += __expf(sc[ch] - mx);
  for (int j0 = 64; j0 < deg; j0 += 8) {
    int j = j0 + e8;
    if (j < deg) {
      int s = csr_src[r0 + j];
      sum += __expf(leaky(as1[(size_t)s * 8 + hh] + addh) - mx);
    }
  }
  sum += __shfl_xor(sum, 8);
  sum += __shfl_xor(sum, 16);
  sum += __shfl_xor(sum, 32);
  sum += __expf(self_sc - mx);
  const float inv = 1.f / (sum + EPS);

  float al[8];
#pragma unroll
  for (int ch = 0; ch < 8; ch++) al[ch] = __expf(sc[ch] - mx) * inv;
  const float al_self_byhh = __expf(self_sc - mx) * inv;

  const int p = lane >> 5, g = lane & 31, hg = g >> 2;
  float acc[8];
#pragma unroll
  for (int i = 0; i < 8; i++) acc[i] = 0.f;

#pragma unroll
  for (int it = 0; it < 32; it++) {
    if (it * 2 < deg) {
      const int   j   = it * 2 + p;
      const int   s_j = __shfl(se[it >> 2], (j & 7) * 8);
      const float a_j = __shfl(al[it >> 2], (j & 7) * 8 + hg);
      bf16x8 x = *(const bf16x8*)(h1 + (size_t)s_j * C1 + g * 8);
#pragma unroll
      for (int i = 0; i < 8; i++) acc[i] += a_j * (float)x[i];
    }
  }
  for (int j0 = 64; j0 < deg; j0 += 8) {
    int j = j0 + e8;
    int se2 = 0; float al2 = 0.f;
    if (j < deg) { se2 = csr_src[r0 + j]; al2 = __expf(leaky(as1[(size_t)se2 * 8 + hh] + addh) - mx) * inv; }
#pragma unroll
    for (int it = 0; it < 4; it++) {
      if (j0 + it * 2 < deg) {
        const int   jj  = it * 2 + p;
        const int   s_j = __shfl(se2, jj * 8);
        const float a_j = __shfl(al2, jj * 8 + hg);
        bf16x8 x = *(const bf16x8*)(h1 + (size_t)s_j * C1 + g * 8);
#pragma unroll
        for (int i = 0; i < 8; i++) acc[i] += a_j * (float)x[i];
      }
    }
  }
#pragma unroll
  for (int i = 0; i < 8; i++) acc[i] += __shfl_xor(acc[i], 32);

  const float a_selfh = __shfl(al_self_byhh, hg);
  if (lane < 32) {
    bf16x8 xs = *(const bf16x8*)(h1 + (size_t)d * C1 + g * 8);
    const float4 b4a = *(const float4*)(b1 + g * 8);
    const float4 b4b = *(const float4*)(b1 + g * 8 + 4);
    bf16x8 o;
    o[0] = (__bf16)fmaxf(acc[0] + a_selfh * (float)xs[0] + b4a.x, 0.f);
    o[1] = (__bf16)fmaxf(acc[1] + a_selfh * (float)xs[1] + b4a.y, 0.f);
    o[2] = (__bf16)fmaxf(acc[2] + a_selfh * (float)xs[2] + b4a.z, 0.f);
    o[3] = (__bf16)fmaxf(acc[3] + a_selfh * (float)xs[3] + b4a.w, 0.f);
    o[4] = (__bf16)fmaxf(acc[4] + a_selfh * (float)xs[4] + b4b.x, 0.f);
    o[5] = (__bf16)fmaxf(acc[5] + a_selfh * (float)xs[5] + b4b.y, 0.f);
    o[6] = (__bf16)fmaxf(acc[6] + a_selfh * (float)xs[6] + b4b.z, 0.f);
    o[7] = (__bf16)fmaxf(acc[7] + a_selfh * (float)xs[7] + b4b.w, 0.f);
    *(bf16x8*)(o1 + (size_t)d * C1 + g * 8) = o;
  }
}

// ---------------- layer-2 gather: no-max softmax + 2-deep pipeline + log_softmax ----------------
__global__ __launch_bounds__(256) void gather2(const int* __restrict__ rowstart,
    const int* __restrict__ csr_src, const __bf16* __restrict__ h2b,
    const float* __restrict__ as2, const float* __restrict__ ad2,
    const float* __restrict__ b2, float* __restrict__ out, int N) {
  const int t = threadIdx.x, lane = t & 63;
  const int d = blockIdx.x * 4 + (t >> 6);
  if (d >= N) return;
  const int r0 = rowstart[d], deg = rowstart[d + 1] - r0;
  const float addd = ad2[d];
  const float self_e = __expf(leaky(as2[d] + addd));

  int se = 0; float ex = 0.f;
  if (lane < deg) { se = csr_src[r0 + lane]; ex = __expf(leaky(as2[se] + addd)); }
  float sum = ex;
  for (int j0 = 64; j0 < deg; j0 += 64) {
    int j = j0 + lane;
    if (j < deg) sum += __expf(leaky(as2[csr_src[r0 + j]] + addd));
  }
#pragma unroll
  for (int o = 1; o < 64; o <<= 1) sum += __shfl_xor(sum, o);
  sum += self_e;
  const float inv = 1.f / (sum + EPS);
  const float alpha = ex * inv;          // 0 for padded edges
  const float al_self = self_e * inv;

  const int e8 = lane >> 3, c8 = lane & 7;
  float acc[8];
#pragma unroll
  for (int i = 0; i < 8; i++) acc[i] = 0.f;

  // 16 edges per guarded group, 2 gathers in flight
#pragma unroll
  for (int itg = 0; itg < 8; itg += 2) {
    if (itg * 8 < deg) {
      const int   sa = __shfl(se, itg * 8 + e8);
      const int   sb = __shfl(se, itg * 8 + 8 + e8);
      const float aa = __shfl(alpha, itg * 8 + e8);
      const float ab = __shfl(alpha, itg * 8 + 8 + e8);
      bf16x8 xa = *(const bf16x8*)(h2b + ((uint32_t)sa * 64u + (uint32_t)(c8 * 8)));
      bf16x8 xb = *(const bf16x8*)(h2b + ((uint32_t)sb * 64u + (uint32_t)(c8 * 8)));
#pragma unroll
      for (int i = 0; i < 8; i++) acc[i] += aa * (float)xa[i];
#pragma unroll
      for (int i = 0; i < 8; i++) acc[i] += ab * (float)xb[i];
    }
  }
  for (int j0 = 64; j0 < deg; j0 += 64) {
    int j = j0 + lane;
    int se2 = 0; float al2 = 0.f;
    if (j < deg) { se2 = csr_src[r0 + j]; al2 = __expf(leaky(as2[se2] + addd)) * inv; }
#pragma unroll
    for (int it = 0; it < 8; it++) {
      if (j0 + it * 8 < deg) {
        const int   jj  = it * 8 + e8;
        const int   s_j = __shfl(se2, jj);
        const float a_j = __shfl(al2, jj);
        bf16x8 x = *(const bf16x8*)(h2b + ((uint32_t)s_j * 64u + (uint32_t)(c8 * 8)));
#pragma unroll
        for (int i = 0; i < 8; i++) acc[i] += a_j * (float)x[i];
      }
    }
  }
#pragma unroll
  for (int i = 0; i < 8; i++) {
    acc[i] += __shfl_xor(acc[i], 8);
    acc[i] += __shfl_xor(acc[i], 16);
    acc[i] += __shfl_xor(acc[i], 32);
  }

  bf16x8 xs = *(const bf16x8*)(h2b + ((uint32_t)d * 64u + (uint32_t)(c8 * 8)));
  const float4 bba = *(const float4*)(b2 + c8 * 8);
  const float4 bbb = *(const float4*)(b2 + c8 * 8 + 4);
  float v[8];
  v[0] = acc[0] + al_self * (float)xs[0] + bba.x;
  v[1] = acc[1] + al_self * (float)xs[1] + bba.y;
  v[2] = acc[2] + al_self * (float)xs[2] + bba.z;
  v[3] = acc[3] + al_self * (float)xs[3] + bba.w;
  v[4] = acc[4] + al_self * (float)xs[4] + bbb.x;
  v[5] = acc[5] + al_self * (float)xs[5] + bbb.y;
  v[6] = acc[6] + al_self * (float)xs[6] + bbb.z;
  v[7] = acc[7] + al_self * (float)xs[7] + bbb.w;
  float m2 = v[0];
#pragma unroll
  for (int i = 1; i < 8; i++) m2 = fmaxf(m2, v[i]);
  m2 = fmaxf(m2, __shfl_xor(m2, 1));
  m2 = fmaxf(m2, __shfl_xor(m2, 2));
  m2 = fmaxf(m2, __shfl_xor(m2, 4));
  float sm = 0.f;
#pragma unroll
  for (int i = 0; i < 8; i++) sm += __expf(v[i] - m2);
  sm += __shfl_xor(sm, 1);
  sm += __shfl_xor(sm, 2);
  sm += __shfl_xor(sm, 4);
  const float lg = m2 + __logf(sm);
  if (lane < 8) {
    float4 o0, o1v;
    o0.x  = v[0] - lg; o0.y  = v[1] - lg; o0.z  = v[2] - lg; o0.w  = v[3] - lg;
    o1v.x = v[4] - lg; o1v.y = v[5] - lg; o1v.z = v[6] - lg; o1v.w = v[7] - lg;
    *(float4*)(out + (size_t)d * CLS + c8 * 8)     = o0;
    *(float4*)(out + (size_t)d * CLS + c8 * 8 + 4) = o1v;
  }
}

extern "C" void kernel_launch(void* const* d_in, const int* in_sizes, int n_in,
                              void* d_out, int out_size, void* d_ws, size_t ws_size,
                              hipStream_t stream) {
  const float* x        = (const float*)d_in[0];
  const int*   ei       = (const int*)d_in[1];
  const float* W1       = (const float*)d_in[2];
  const float* att_src1 = (const float*)d_in[3];
  const float* att_dst1 = (const float*)d_in[4];
  const float* b1       = (const float*)d_in[5];
  const float* W2       = (const float*)d_in[6];
  const float* att_src2 = (const float*)d_in[7];
  const float* att_dst2 = (const float*)d_in[8];
  const float* b2       = (const float*)d_in[9];
  float* out = (float*)d_out;

  const int N  = in_sizes[0] / F_IN;   // 50000
  const int E  = in_sizes[1] / 2;      // 800000
  const int NB = (N + 255) / 256;

  char* ws = (char*)d_ws;
  size_t off = 0;
  auto alloc = [&](size_t bytes) -> void* {
    void* p = ws + off;
    off += (bytes + 255) & ~(size_t)255;
    return p;
  };
  __bf16* h1  = (__bf16*)alloc((size_t)N * C1 * 2);
  __bf16* o1  = (__bf16*)alloc((size_t)N * C1 * 2);
  float*  as1 = (float*)alloc((size_t)N * HEADS * 4);
  float*  ad1 = (float*)alloc((size_t)N * HEADS * 4);
  __bf16* h2b = (__bf16*)alloc((size_t)N * CLS * 2);
  float*  as2 = (float*)alloc((size_t)N * 4);
  float*  ad2 = (float*)alloc((size_t)N * 4);
  int* deg      = (int*)alloc((size_t)N * 4);
  int* rowstart = (int*)alloc((size_t)(N + 1) * 4);
  int* cur      = (int*)alloc((size_t)N * 4);
  int* csr_src  = (int*)alloc((size_t)E * 4);
  int* bsum     = (int*)alloc((size_t)NB * 4);
  __bf16* w1t = (__bf16*)alloc((size_t)C1 * F_IN * 2);
  __bf16* w2t = (__bf16*)alloc((size_t)CLS * C1 * 2);

  // ---- prep: weight casts + degree histogram ----
  hipMemsetAsync(deg, 0, (size_t)N * 4, stream);
  prep<<<72 + (E + 255) / 256, 256, 0, stream>>>(W1, W2, ei, w1t, w2t, deg, E);

  // ---- parallel scan -> rowstart, cur ----
  scan_k1<<<NB, 256, 0, stream>>>(deg, bsum, N);
  scan_k2<<<1, 256, 0, stream>>>(bsum, NB);
  scan_k3<<<NB, 256, 0, stream>>>(deg, bsum, rowstart, cur, N);
  scatter_csr<<<(E + 255) / 256, 256, 0, stream>>>(ei, cur, csr_src, E);

  // ---- layer 1: GEMM (BM=128 x BN=256, 8 waves, A read once, B via gload_lds dbuf) ----
  gemm1_fused<<<(N + 127) / 128, 512, 0, stream>>>(x, w1t, h1, att_src1, att_dst1, as1, ad1, N);
  gather1<<<(N + 3) / 4, 256, 0, stream>>>(rowstart, csr_src, h1, as1, ad1, b1, o1, N);

  // ---- layer 2: GEMM + scores fused ----
  gemm2_fused<<<(N + 127) / 128, 256, 0, stream>>>(o1, w2t, h2b, att_src2, att_dst2, as2, ad2, N);
  gather2<<<(N + 3) / 4, 256, 0, stream>>>(rowstart, csr_src, h2b, as2, ad2, b2, out, N);
}

// Round 9
// 397.157 us; speedup vs baseline: 1.0032x; 1.0032x over previous
//
#include <hip/hip_runtime.h>
#include <hip/hip_bf16.h>
#include <stdint.h>

#define F_IN 512
#define HID 32
#define HEADS 8
#define C1 (HEADS*HID)   // 256
#define CLS 64
#define NEG 0.2f
#define EPS 1e-16f

typedef __bf16 bf16x8 __attribute__((ext_vector_type(8)));
typedef __bf16 bf16x4 __attribute__((ext_vector_type(4)));
typedef float  f32x4  __attribute__((ext_vector_type(4)));

__device__ __forceinline__ float leaky(float v) { return v > 0.f ? v : NEG * v; }

__device__ __forceinline__ bf16x8 cvt8(float4 a, float4 b) {
  bf16x8 o;
  o[0] = (__bf16)a.x; o[1] = (__bf16)a.y; o[2] = (__bf16)a.z; o[3] = (__bf16)a.w;
  o[4] = (__bf16)b.x; o[5] = (__bf16)b.y; o[6] = (__bf16)b.z; o[7] = (__bf16)b.w;
  return o;
}

// ---------------- fused prep: cvt_w1t | cvt_w2t | count_deg ----------------
__global__ __launch_bounds__(256) void prep(const float* __restrict__ W1,
    const float* __restrict__ W2, const int* __restrict__ ei,
    __bf16* __restrict__ w1t, __bf16* __restrict__ w2t,
    int* __restrict__ deg, int E) {
  const int b = blockIdx.x, t = threadIdx.x;
  if (b < 64) {
    int i = b * 256 + t;
    int o0 = i * 8;
    int c = o0 >> 9, k0 = o0 & 511;
    bf16x8 o;
#pragma unroll
    for (int j = 0; j < 8; j++) o[j] = (__bf16)W1[(size_t)(k0 + j) * C1 + c];
    *(bf16x8*)(w1t + (size_t)o0) = o;
  } else if (b < 72) {
    int i = (b - 64) * 256 + t;
    int o0 = i * 8;
    int c = o0 >> 8, k0 = o0 & 255;
    bf16x8 o;
#pragma unroll
    for (int j = 0; j < 8; j++) o[j] = (__bf16)W2[(size_t)(k0 + j) * CLS + c];
    *(bf16x8*)(w2t + (size_t)o0) = o;
  } else {
    int e = (b - 72) * 256 + t;
    if (e < E) atomicAdd(&deg[ei[E + e]], 1);
  }
}

// ---------------- parallel exclusive scan ----------------
__global__ __launch_bounds__(256) void scan_k1(const int* __restrict__ deg,
    int* __restrict__ bsum, int N) {
  __shared__ int ws[4];
  const int t = threadIdx.x, lane = t & 63, wid = t >> 6;
  int i = blockIdx.x * 256 + t;
  int v = (i < N) ? deg[i] : 0;
#pragma unroll
  for (int o = 1; o < 64; o <<= 1) v += __shfl_xor(v, o);
  if (lane == 0) ws[wid] = v;
  __syncthreads();
  if (t == 0) bsum[blockIdx.x] = ws[0] + ws[1] + ws[2] + ws[3];
}

__global__ __launch_bounds__(256) void scan_k2(int* __restrict__ bsum, int nb) {
  __shared__ int wsum[4];
  __shared__ int carry_s;
  const int t = threadIdx.x, lane = t & 63, wid = t >> 6;
  if (t == 0) carry_s = 0;
  __syncthreads();
  for (int base = 0; base < nb; base += 256) {
    int i = base + t;
    int v = (i < nb) ? bsum[i] : 0;
    int inc = v;
#pragma unroll
    for (int o = 1; o < 64; o <<= 1) { int x = __shfl_up(inc, o); if (lane >= o) inc += x; }
    if (lane == 63) wsum[wid] = inc;
    __syncthreads();
    int woff = 0;
    for (int w = 0; w < wid; w++) woff += wsum[w];
    int excl = carry_s + woff + inc - v;
    if (i < nb) bsum[i] = excl;
    __syncthreads();
    if (t == 0) carry_s += wsum[0] + wsum[1] + wsum[2] + wsum[3];
    __syncthreads();
  }
}

__global__ __launch_bounds__(256) void scan_k3(const int* __restrict__ deg,
    const int* __restrict__ bsum, int* __restrict__ rowstart,
    int* __restrict__ cur, int N) {
  __shared__ int wsum[4];
  const int t = threadIdx.x, lane = t & 63, wid = t >> 6;
  int i = blockIdx.x * 256 + t;
  int v = (i < N) ? deg[i] : 0;
  int inc = v;
#pragma unroll
  for (int o = 1; o < 64; o <<= 1) { int x = __shfl_up(inc, o); if (lane >= o) inc += x; }
  if (lane == 63) wsum[wid] = inc;
  __syncthreads();
  int woff = 0;
  for (int w = 0; w < wid; w++) woff += wsum[w];
  int excl = bsum[blockIdx.x] + woff + inc - v;
  if (i < N) { rowstart[i] = excl; cur[i] = excl; }
  if (i == N - 1) rowstart[N] = excl + v;
}

__global__ __launch_bounds__(256) void scatter_csr(const int* __restrict__ ei,
    int* __restrict__ cur, int* __restrict__ csr_src, int E) {
  int e = blockIdx.x * 256 + threadIdx.x;
  if (e >= E) return;
  int s = ei[e], d = ei[E + e];
  int pos = atomicAdd(&cur[d], 1);
  csr_src[pos] = s;
}

// ---------------- GEMM1 fused: h1 = x @ w1t^T, BM=128 x BN=256, 8 waves ----------------
// A read once per block; register prefetch (r6-proven) + double-buffered LDS ->
// ONE barrier per K-step (16 vs 32): with only ~1.5 blocks/CU, barrier stalls are exposed.
__global__ __launch_bounds__(512) void gemm1_fused(const float* __restrict__ A,
    const __bf16* __restrict__ Bt, __bf16* __restrict__ C,
    const float* __restrict__ asw, const float* __restrict__ adw,
    float* __restrict__ a_src, float* __restrict__ a_dst, int M) {
  __shared__ __bf16 Al[2][128 * 32];
  __shared__ __bf16 Bl[2][256 * 32];
  const int tid = threadIdx.x, lane = tid & 63, wave = tid >> 6;  // wave 0..7
  const int lm = lane & 15, q = lane >> 4;
  const int wr = ((wave >> 1) & 1) * 64;                 // row half: 0 or 64
  const int cb = (wave >> 2) * 128 + (wave & 1) * 64;    // col block: 0,64,128,192
  const int bm = blockIdx.x * 128;
  const int srow = tid >> 2, skc = (tid & 3) * 8;        // srow 0..127

  f32x4 acc[4][4];
#pragma unroll
  for (int i = 0; i < 4; i++)
#pragma unroll
    for (int j = 0; j < 4; j++) acc[i][j] = (f32x4){0.f, 0.f, 0.f, 0.f};

  const int ra = min(bm + srow, M - 1);

  float4 a0, a1;
  bf16x8 vb0, vb1;
  // tile 0 -> regs -> buf0
  a0  = *(const float4*)(A + (size_t)ra * 512 + skc);
  a1  = *(const float4*)(A + (size_t)ra * 512 + skc + 4);
  vb0 = *(const bf16x8*)(Bt + (size_t)srow * 512 + skc);
  vb1 = *(const bf16x8*)(Bt + (size_t)(srow + 128) * 512 + skc);
  *(bf16x8*)(&Al[0][srow * 32 + skc])         = cvt8(a0, a1);
  *(bf16x8*)(&Bl[0][srow * 32 + skc])         = vb0;
  *(bf16x8*)(&Bl[0][(srow + 128) * 32 + skc]) = vb1;
  // tile 1 -> regs
  a0  = *(const float4*)(A + (size_t)ra * 512 + 32 + skc);
  a1  = *(const float4*)(A + (size_t)ra * 512 + 32 + skc + 4);
  vb0 = *(const bf16x8*)(Bt + (size_t)srow * 512 + 32 + skc);
  vb1 = *(const bf16x8*)(Bt + (size_t)(srow + 128) * 512 + 32 + skc);
  __syncthreads();   // buf0 visible

  for (int kk = 0; kk < 16; kk++) {
    const int cur = kk & 1, nxt = cur ^ 1;
    if (kk + 1 < 16) {
      // regs hold tile kk+1 -> write to nxt buffer
      *(bf16x8*)(&Al[nxt][srow * 32 + skc])         = cvt8(a0, a1);
      *(bf16x8*)(&Bl[nxt][srow * 32 + skc])         = vb0;
      *(bf16x8*)(&Bl[nxt][(srow + 128) * 32 + skc]) = vb1;
      if (kk + 2 < 16) {
        const int k0 = (kk + 2) * 32;
        a0  = *(const float4*)(A + (size_t)ra * 512 + k0 + skc);
        a1  = *(const float4*)(A + (size_t)ra * 512 + k0 + skc + 4);
        vb0 = *(const bf16x8*)(Bt + (size_t)srow * 512 + k0 + skc);
        vb1 = *(const bf16x8*)(Bt + (size_t)(srow + 128) * 512 + k0 + skc);
      }
    }
    bf16x8 af[4], bfr[4];
#pragma unroll
    for (int mi = 0; mi < 4; mi++)
      af[mi] = *(const bf16x8*)(&Al[cur][(wr + mi * 16 + lm) * 32 + q * 8]);
#pragma unroll
    for (int ni = 0; ni < 4; ni++)
      bfr[ni] = *(const bf16x8*)(&Bl[cur][(cb + ni * 16 + lm) * 32 + q * 8]);
#pragma unroll
    for (int mi = 0; mi < 4; mi++)
#pragma unroll
      for (int ni = 0; ni < 4; ni++)
        acc[mi][ni] = __builtin_amdgcn_mfma_f32_16x16x32_bf16(af[mi], bfr[ni], acc[mi][ni], 0, 0, 0);
    __syncthreads();   // my reads of cur done; my writes to nxt visible
  }

  // store h1 (bf16)
#pragma unroll
  for (int mi = 0; mi < 4; mi++) {
#pragma unroll
    for (int ni = 0; ni < 4; ni++) {
      const int col = cb + ni * 16 + lm;
#pragma unroll
      for (int r = 0; r < 4; r++) {
        const int row = bm + wr + mi * 16 + q * 4 + r;
        if (row < M) C[(size_t)row * C1 + col] = (__bf16)acc[mi][ni][r];
      }
    }
  }

  // fused scores from fp32 acc: this wave covers heads h0, h0+1 (cols cb .. cb+63)
  {
    const int h0 = cb >> 5;
    float ws[4], wd[4];
#pragma unroll
    for (int ni = 0; ni < 4; ni++) {
      ws[ni] = asw[cb + ni * 16 + lm];
      wd[ni] = adw[cb + ni * 16 + lm];
    }
#pragma unroll
    for (int mi = 0; mi < 4; mi++) {
#pragma unroll
      for (int r = 0; r < 4; r++) {
        float ps0 = acc[mi][0][r] * ws[0] + acc[mi][1][r] * ws[1];
        float ps1 = acc[mi][2][r] * ws[2] + acc[mi][3][r] * ws[3];
        float pd0 = acc[mi][0][r] * wd[0] + acc[mi][1][r] * wd[1];
        float pd1 = acc[mi][2][r] * wd[2] + acc[mi][3][r] * wd[3];
#pragma unroll
        for (int o = 1; o <= 8; o <<= 1) {
          ps0 += __shfl_xor(ps0, o); ps1 += __shfl_xor(ps1, o);
          pd0 += __shfl_xor(pd0, o); pd1 += __shfl_xor(pd1, o);
        }
        if (lm == 0) {
          const int row = bm + wr + mi * 16 + q * 4 + r;
          if (row < M) {
            a_src[(size_t)row * 8 + h0]     = ps0;
            a_src[(size_t)row * 8 + h0 + 1] = ps1;
            a_dst[(size_t)row * 8 + h0]     = pd0;
            a_dst[(size_t)row * 8 + h0 + 1] = pd1;
          }
        }
      }
    }
  }
}

// ---------------- GEMM2 fused: h2b = o1 @ w2t^T (bf16 out) + att scores 2 ----------------
__global__ __launch_bounds__(256) void gemm2_fused(const __bf16* __restrict__ A,
    const __bf16* __restrict__ Bt, __bf16* __restrict__ C,
    const float* __restrict__ asw, const float* __restrict__ adw,
    float* __restrict__ a_src, float* __restrict__ a_dst, int M) {
  __shared__ __bf16 Al[128 * 32];
  __shared__ __bf16 Bl[64 * 32];
  __shared__ float sred[128][2][2];
  const int tid = threadIdx.x, lane = tid & 63, wave = tid >> 6;
  const int lm = lane & 15, q = lane >> 4;
  const int wr = (wave >> 1) * 64, wc = (wave & 1) * 32;
  const int bm = blockIdx.x * 128;
  const int srow = tid >> 2, skc = (tid & 3) * 8;

  f32x4 acc[4][2];
#pragma unroll
  for (int i = 0; i < 4; i++)
#pragma unroll
    for (int j = 0; j < 2; j++) acc[i][j] = (f32x4){0.f, 0.f, 0.f, 0.f};

  const int ra0 = min(bm + srow, M - 1);
  const int ra1 = min(bm + srow + 64, M - 1);

  bf16x8 va0, va1, vb;
  va0 = *(const bf16x8*)(A + (size_t)ra0 * C1 + skc);
  va1 = *(const bf16x8*)(A + (size_t)ra1 * C1 + skc);
  vb  = *(const bf16x8*)(Bt + (size_t)srow * C1 + skc);

  for (int kk = 0; kk < 8; kk++) {
    __syncthreads();
    *(bf16x8*)(Al + srow * 32 + skc)        = va0;
    *(bf16x8*)(Al + (srow + 64) * 32 + skc) = va1;
    *(bf16x8*)(Bl + srow * 32 + skc)        = vb;
    __syncthreads();
    if (kk + 1 < 8) {
      const int k0 = (kk + 1) * 32;
      va0 = *(const bf16x8*)(A + (size_t)ra0 * C1 + k0 + skc);
      va1 = *(const bf16x8*)(A + (size_t)ra1 * C1 + k0 + skc);
      vb  = *(const bf16x8*)(Bt + (size_t)srow * C1 + k0 + skc);
    }
    bf16x8 af[4], bfr[2];
#pragma unroll
    for (int mi = 0; mi < 4; mi++)
      af[mi] = *(const bf16x8*)(Al + (wr + mi * 16 + lm) * 32 + q * 8);
#pragma unroll
    for (int ni = 0; ni < 2; ni++)
      bfr[ni] = *(const bf16x8*)(Bl + (wc + ni * 16 + lm) * 32 + q * 8);
#pragma unroll
    for (int mi = 0; mi < 4; mi++)
#pragma unroll
      for (int ni = 0; ni < 2; ni++)
        acc[mi][ni] = __builtin_amdgcn_mfma_f32_16x16x32_bf16(af[mi], bfr[ni], acc[mi][ni], 0, 0, 0);
  }

  float ws[2], wd[2];
#pragma unroll
  for (int ni = 0; ni < 2; ni++) {
    ws[ni] = asw[wc + ni * 16 + lm];
    wd[ni] = adw[wc + ni * 16 + lm];
  }
#pragma unroll
  for (int mi = 0; mi < 4; mi++) {
#pragma unroll
    for (int ni = 0; ni < 2; ni++) {
      const int col = wc + ni * 16 + lm;
#pragma unroll
      for (int r = 0; r < 4; r++) {
        const int row = bm + wr + mi * 16 + q * 4 + r;
        if (row < M) C[(size_t)row * CLS + col] = (__bf16)acc[mi][ni][r];
      }
    }
#pragma unroll
    for (int r = 0; r < 4; r++) {
      float ps = acc[mi][0][r] * ws[0] + acc[mi][1][r] * ws[1];
      float pd = acc[mi][0][r] * wd[0] + acc[mi][1][r] * wd[1];
#pragma unroll
      for (int o = 1; o <= 8; o <<= 1) { ps += __shfl_xor(ps, o); pd += __shfl_xor(pd, o); }
      if (lm == 0) {
        const int rl = wr + mi * 16 + q * 4 + r;
        sred[rl][wave & 1][0] = ps;
        sred[rl][wave & 1][1] = pd;
      }
    }
  }
  __syncthreads();
  if (tid < 128) {
    const int row = bm + tid;
    if (row < M) {
      a_src[row] = sred[tid][0][0] + sred[tid][1][0];
      a_dst[row] = sred[tid][0][1] + sred[tid][1][1];
    }
  }
}

// ---------------- layer-1 gather (r0-proven exact: ~76.7µs, VGPR 36, occ 61%) ----------------
__global__ __launch_bounds__(256) void gather1(const int* __restrict__ rowstart,
    const int* __restrict__ csr_src, const __bf16* __restrict__ h1,
    const float* __restrict__ as1, const float* __restrict__ ad1,
    const float* __restrict__ b1, __bf16* __restrict__ o1, int N) {
  const int t = threadIdx.x;
  const int d = blockIdx.x * 4 + (t >> 6);
  if (d >= N) return;
  const int lane = t & 63;
  const int e8 = lane >> 3, hh = lane & 7;
  const int r0 = rowstart[d];
  const int deg = rowstart[d + 1] - r0;

  const float addh = ad1[(size_t)d * 8 + hh];
  const float self_sc = leaky(as1[(size_t)d * 8 + hh] + addh);

  int   se[8];
  float sc[8];
#pragma unroll
  for (int ch = 0; ch < 8; ch++) {
    const int j = ch * 8 + e8;
    se[ch] = 0; sc[ch] = -3.4e38f;
    if (j < deg) {
      int s = csr_src[r0 + j];
      se[ch] = s;
      sc[ch] = leaky(as1[(size_t)s * 8 + hh] + addh);
    }
  }
  float mx = -3.4e38f;
#pragma unroll
  for (int ch = 0; ch < 8; ch++) mx = fmaxf(mx, sc[ch]);
  for (int j0 = 64; j0 < deg; j0 += 8) {
    int j = j0 + e8;
    if (j < deg) {
      int s = csr_src[r0 + j];
      mx = fmaxf(mx, leaky(as1[(size_t)s * 8 + hh] + addh));
    }
  }
  mx = fmaxf(mx, __shfl_xor(mx, 8));
  mx = fmaxf(mx, __shfl_xor(mx, 16));
  mx = fmaxf(mx, __shfl_xor(mx, 32));
  mx = fmaxf(mx, self_sc);

  float sum = 0.f;
#pragma unroll
  for (int ch = 0; ch < 8; ch++)
    if (ch * 8 + e8 < deg) sum += __expf(sc[ch] - mx);
  for (int j0 = 64; j0 < deg; j0 += 8) {
    int j = j0 + e8;
    if (j < deg) {
      int s = csr_src[r0 + j];
      sum += __expf(leaky(as1[(size_t)s * 8 + hh] + addh) - mx);
    }
  }
  sum += __shfl_xor(sum, 8);
  sum += __shfl_xor(sum, 16);
  sum += __shfl_xor(sum, 32);
  sum += __expf(self_sc - mx);
  const float inv = 1.f / (sum + EPS);

  float al[8];
#pragma unroll
  for (int ch = 0; ch < 8; ch++) al[ch] = __expf(sc[ch] - mx) * inv;
  const float al_self_byhh = __expf(self_sc - mx) * inv;

  const int p = lane >> 5, g = lane & 31, hg = g >> 2;
  float acc[8];
#pragma unroll
  for (int i = 0; i < 8; i++) acc[i] = 0.f;

#pragma unroll
  for (int it = 0; it < 32; it++) {
    if (it * 2 < deg) {
      const int   j   = it * 2 + p;
      const int   s_j = __shfl(se[it >> 2], (j & 7) * 8);
      const float a_j = __shfl(al[it >> 2], (j & 7) * 8 + hg);
      bf16x8 x = *(const bf16x8*)(h1 + (size_t)s_j * C1 + g * 8);
#pragma unroll
      for (int i = 0; i < 8; i++) acc[i] += a_j * (float)x[i];
    }
  }
  for (int j0 = 64; j0 < deg; j0 += 8) {
    int j = j0 + e8;
    int se2 = 0; float al2 = 0.f;
    if (j < deg) { se2 = csr_src[r0 + j]; al2 = __expf(leaky(as1[(size_t)se2 * 8 + hh] + addh) - mx) * inv; }
#pragma unroll
    for (int it = 0; it < 4; it++) {
      if (j0 + it * 2 < deg) {
        const int   jj  = it * 2 + p;
        const int   s_j = __shfl(se2, jj * 8);
        const float a_j = __shfl(al2, jj * 8 + hg);
        bf16x8 x = *(const bf16x8*)(h1 + (size_t)s_j * C1 + g * 8);
#pragma unroll
        for (int i = 0; i < 8; i++) acc[i] += a_j * (float)x[i];
      }
    }
  }
#pragma unroll
  for (int i = 0; i < 8; i++) acc[i] += __shfl_xor(acc[i], 32);

  const float a_selfh = __shfl(al_self_byhh, hg);
  if (lane < 32) {
    bf16x8 xs = *(const bf16x8*)(h1 + (size_t)d * C1 + g * 8);
    const float4 b4a = *(const float4*)(b1 + g * 8);
    const float4 b4b = *(const float4*)(b1 + g * 8 + 4);
    bf16x8 o;
    o[0] = (__bf16)fmaxf(acc[0] + a_selfh * (float)xs[0] + b4a.x, 0.f);
    o[1] = (__bf16)fmaxf(acc[1] + a_selfh * (float)xs[1] + b4a.y, 0.f);
    o[2] = (__bf16)fmaxf(acc[2] + a_selfh * (float)xs[2] + b4a.z, 0.f);
    o[3] = (__bf16)fmaxf(acc[3] + a_selfh * (float)xs[3] + b4a.w, 0.f);
    o[4] = (__bf16)fmaxf(acc[4] + a_selfh * (float)xs[4] + b4b.x, 0.f);
    o[5] = (__bf16)fmaxf(acc[5] + a_selfh * (float)xs[5] + b4b.y, 0.f);
    o[6] = (__bf16)fmaxf(acc[6] + a_selfh * (float)xs[6] + b4b.z, 0.f);
    o[7] = (__bf16)fmaxf(acc[7] + a_selfh * (float)xs[7] + b4b.w, 0.f);
    *(bf16x8*)(o1 + (size_t)d * C1 + g * 8) = o;
  }
}

// ---------------- layer-2 gather: no-max softmax + 2-deep pipeline + log_softmax ----------------
__global__ __launch_bounds__(256) void gather2(const int* __restrict__ rowstart,
    const int* __restrict__ csr_src, const __bf16* __restrict__ h2b,
    const float* __restrict__ as2, const float* __restrict__ ad2,
    const float* __restrict__ b2, float* __restrict__ out, int N) {
  const int t = threadIdx.x, lane = t & 63;
  const int d = blockIdx.x * 4 + (t >> 6);
  if (d >= N) return;
  const int r0 = rowstart[d], deg = rowstart[d + 1] - r0;
  const float addd = ad2[d];
  const float self_e = __expf(leaky(as2[d] + addd));

  int se = 0; float ex = 0.f;
  if (lane < deg) { se = csr_src[r0 + lane]; ex = __expf(leaky(as2[se] + addd)); }
  float sum = ex;
  for (int j0 = 64; j0 < deg; j0 += 64) {
    int j = j0 + lane;
    if (j < deg) sum += __expf(leaky(as2[csr_src[r0 + j]] + addd));
  }
#pragma unroll
  for (int o = 1; o < 64; o <<= 1) sum += __shfl_xor(sum, o);
  sum += self_e;
  const float inv = 1.f / (sum + EPS);
  const float alpha = ex * inv;          // 0 for padded edges
  const float al_self = self_e * inv;

  const int e8 = lane >> 3, c8 = lane & 7;
  float acc[8];
#pragma unroll
  for (int i = 0; i < 8; i++) acc[i] = 0.f;

  // 16 edges per guarded group, 2 gathers in flight
#pragma unroll
  for (int itg = 0; itg < 8; itg += 2) {
    if (itg * 8 < deg) {
      const int   sa = __shfl(se, itg * 8 + e8);
      const int   sb = __shfl(se, itg * 8 + 8 + e8);
      const float aa = __shfl(alpha, itg * 8 + e8);
      const float ab = __shfl(alpha, itg * 8 + 8 + e8);
      bf16x8 xa = *(const bf16x8*)(h2b + ((uint32_t)sa * 64u + (uint32_t)(c8 * 8)));
      bf16x8 xb = *(const bf16x8*)(h2b + ((uint32_t)sb * 64u + (uint32_t)(c8 * 8)));
#pragma unroll
      for (int i = 0; i < 8; i++) acc[i] += aa * (float)xa[i];
#pragma unroll
      for (int i = 0; i < 8; i++) acc[i] += ab * (float)xb[i];
    }
  }
  for (int j0 = 64; j0 < deg; j0 += 64) {
    int j = j0 + lane;
    int se2 = 0; float al2 = 0.f;
    if (j < deg) { se2 = csr_src[r0 + j]; al2 = __expf(leaky(as2[se2] + addd)) * inv; }
#pragma unroll
    for (int it = 0; it < 8; it++) {
      if (j0 + it * 8 < deg) {
        const int   jj  = it * 8 + e8;
        const int   s_j = __shfl(se2, jj);
        const float a_j = __shfl(al2, jj);
        bf16x8 x = *(const bf16x8*)(h2b + ((uint32_t)s_j * 64u + (uint32_t)(c8 * 8)));
#pragma unroll
        for (int i = 0; i < 8; i++) acc[i] += a_j * (float)x[i];
      }
    }
  }
#pragma unroll
  for (int i = 0; i < 8; i++) {
    acc[i] += __shfl_xor(acc[i], 8);
    acc[i] += __shfl_xor(acc[i], 16);
    acc[i] += __shfl_xor(acc[i], 32);
  }

  bf16x8 xs = *(const bf16x8*)(h2b + ((uint32_t)d * 64u + (uint32_t)(c8 * 8)));
  const float4 bba = *(const float4*)(b2 + c8 * 8);
  const float4 bbb = *(const float4*)(b2 + c8 * 8 + 4);
  float v[8];
  v[0] = acc[0] + al_self * (float)xs[0] + bba.x;
  v[1] = acc[1] + al_self * (float)xs[1] + bba.y;
  v[2] = acc[2] + al_self * (float)xs[2] + bba.z;
  v[3] = acc[3] + al_self * (float)xs[3] + bba.w;
  v[4] = acc[4] + al_self * (float)xs[4] + bbb.x;
  v[5] = acc[5] + al_self * (float)xs[5] + bbb.y;
  v[6] = acc[6] + al_self * (float)xs[6] + bbb.z;
  v[7] = acc[7] + al_self * (float)xs[7] + bbb.w;
  float m2 = v[0];
#pragma unroll
  for (int i = 1; i < 8; i++) m2 = fmaxf(m2, v[i]);
  m2 = fmaxf(m2, __shfl_xor(m2, 1));
  m2 = fmaxf(m2, __shfl_xor(m2, 2));
  m2 = fmaxf(m2, __shfl_xor(m2, 4));
  float sm = 0.f;
#pragma unroll
  for (int i = 0; i < 8; i++) sm += __expf(v[i] - m2);
  sm += __shfl_xor(sm, 1);
  sm += __shfl_xor(sm, 2);
  sm += __shfl_xor(sm, 4);
  const float lg = m2 + __logf(sm);
  if (lane < 8) {
    float4 o0, o1v;
    o0.x  = v[0] - lg; o0.y  = v[1] - lg; o0.z  = v[2] - lg; o0.w  = v[3] - lg;
    o1v.x = v[4] - lg; o1v.y = v[5] - lg; o1v.z = v[6] - lg; o1v.w = v[7] - lg;
    *(float4*)(out + (size_t)d * CLS + c8 * 8)     = o0;
    *(float4*)(out + (size_t)d * CLS + c8 * 8 + 4) = o1v;
  }
}

extern "C" void kernel_launch(void* const* d_in, const int* in_sizes, int n_in,
                              void* d_out, int out_size, void* d_ws, size_t ws_size,
                              hipStream_t stream) {
  const float* x        = (const float*)d_in[0];
  const int*   ei       = (const int*)d_in[1];
  const float* W1       = (const float*)d_in[2];
  const float* att_src1 = (const float*)d_in[3];
  const float* att_dst1 = (const float*)d_in[4];
  const float* b1       = (const float*)d_in[5];
  const float* W2       = (const float*)d_in[6];
  const float* att_src2 = (const float*)d_in[7];
  const float* att_dst2 = (const float*)d_in[8];
  const float* b2       = (const float*)d_in[9];
  float* out = (float*)d_out;

  const int N  = in_sizes[0] / F_IN;   // 50000
  const int E  = in_sizes[1] / 2;      // 800000
  const int NB = (N + 255) / 256;

  char* ws = (char*)d_ws;
  size_t off = 0;
  auto alloc = [&](size_t bytes) -> void* {
    void* p = ws + off;
    off += (bytes + 255) & ~(size_t)255;
    return p;
  };
  __bf16* h1  = (__bf16*)alloc((size_t)N * C1 * 2);
  __bf16* o1  = (__bf16*)alloc((size_t)N * C1 * 2);
  float*  as1 = (float*)alloc((size_t)N * HEADS * 4);
  float*  ad1 = (float*)alloc((size_t)N * HEADS * 4);
  __bf16* h2b = (__bf16*)alloc((size_t)N * CLS * 2);
  float*  as2 = (float*)alloc((size_t)N * 4);
  float*  ad2 = (float*)alloc((size_t)N * 4);
  int* deg      = (int*)alloc((size_t)N * 4);
  int* rowstart = (int*)alloc((size_t)(N + 1) * 4);
  int* cur      = (int*)alloc((size_t)N * 4);
  int* csr_src  = (int*)alloc((size_t)E * 4);
  int* bsum     = (int*)alloc((size_t)NB * 4);
  __bf16* w1t = (__bf16*)alloc((size_t)C1 * F_IN * 2);
  __bf16* w2t = (__bf16*)alloc((size_t)CLS * C1 * 2);

  // ---- prep: weight casts + degree histogram ----
  hipMemsetAsync(deg, 0, (size_t)N * 4, stream);
  prep<<<72 + (E + 255) / 256, 256, 0, stream>>>(W1, W2, ei, w1t, w2t, deg, E);

  // ---- parallel scan -> rowstart, cur ----
  scan_k1<<<NB, 256, 0, stream>>>(deg, bsum, N);
  scan_k2<<<1, 256, 0, stream>>>(bsum, NB);
  scan_k3<<<NB, 256, 0, stream>>>(deg, bsum, rowstart, cur, N);
  scatter_csr<<<(E + 255) / 256, 256, 0, stream>>>(ei, cur, csr_src, E);

  // ---- layer 1: GEMM (BM=128 x BN=256, 8 waves, A read once, single-barrier dbuf) ----
  gemm1_fused<<<(N + 127) / 128, 512, 0, stream>>>(x, w1t, h1, att_src1, att_dst1, as1, ad1, N);
  gather1<<<(N + 3) / 4, 256, 0, stream>>>(rowstart, csr_src, h1, as1, ad1, b1, o1, N);

  // ---- layer 2: GEMM + scores fused ----
  gemm2_fused<<<(N + 127) / 128, 256, 0, stream>>>(o1, w2t, h2b, att_src2, att_dst2, as2, ad2, N);
  gather2<<<(N + 3) / 4, 256, 0, stream>>>(rowstart, csr_src, h2b, as2, ad2, b2, out, N);
}

// Round 10
// 392.802 us; speedup vs baseline: 1.0144x; 1.0111x over previous
//
#include <hip/hip_runtime.h>
#include <hip/hip_bf16.h>
#include <stdint.h>

#define F_IN 512
#define HID 32
#define HEADS 8
#define C1 (HEADS*HID)   // 256
#define CLS 64
#define NEG 0.2f
#define EPS 1e-16f

typedef __bf16 bf16x8 __attribute__((ext_vector_type(8)));
typedef __bf16 bf16x4 __attribute__((ext_vector_type(4)));
typedef float  f32x4  __attribute__((ext_vector_type(4)));

__device__ __forceinline__ float leaky(float v) { return v > 0.f ? v : NEG * v; }

__device__ __forceinline__ bf16x8 cvt8(float4 a, float4 b) {
  bf16x8 o;
  o[0] = (__bf16)a.x; o[1] = (__bf16)a.y; o[2] = (__bf16)a.z; o[3] = (__bf16)a.w;
  o[4] = (__bf16)b.x; o[5] = (__bf16)b.y; o[6] = (__bf16)b.z; o[7] = (__bf16)b.w;
  return o;
}

// ---------------- fused prep: cvt_w1t | cvt_w2t | count_deg ----------------
__global__ __launch_bounds__(256) void prep(const float* __restrict__ W1,
    const float* __restrict__ W2, const int* __restrict__ ei,
    __bf16* __restrict__ w1t, __bf16* __restrict__ w2t,
    int* __restrict__ deg, int E) {
  const int b = blockIdx.x, t = threadIdx.x;
  if (b < 64) {
    int i = b * 256 + t;
    int o0 = i * 8;
    int c = o0 >> 9, k0 = o0 & 511;
    bf16x8 o;
#pragma unroll
    for (int j = 0; j < 8; j++) o[j] = (__bf16)W1[(size_t)(k0 + j) * C1 + c];
    *(bf16x8*)(w1t + (size_t)o0) = o;
  } else if (b < 72) {
    int i = (b - 64) * 256 + t;
    int o0 = i * 8;
    int c = o0 >> 8, k0 = o0 & 255;
    bf16x8 o;
#pragma unroll
    for (int j = 0; j < 8; j++) o[j] = (__bf16)W2[(size_t)(k0 + j) * CLS + c];
    *(bf16x8*)(w2t + (size_t)o0) = o;
  } else {
    int e = (b - 72) * 256 + t;
    if (e < E) atomicAdd(&deg[ei[E + e]], 1);
  }
}

// ---------------- parallel exclusive scan ----------------
__global__ __launch_bounds__(256) void scan_k1(const int* __restrict__ deg,
    int* __restrict__ bsum, int N) {
  __shared__ int ws[4];
  const int t = threadIdx.x, lane = t & 63, wid = t >> 6;
  int i = blockIdx.x * 256 + t;
  int v = (i < N) ? deg[i] : 0;
#pragma unroll
  for (int o = 1; o < 64; o <<= 1) v += __shfl_xor(v, o);
  if (lane == 0) ws[wid] = v;
  __syncthreads();
  if (t == 0) bsum[blockIdx.x] = ws[0] + ws[1] + ws[2] + ws[3];
}

__global__ __launch_bounds__(256) void scan_k2(int* __restrict__ bsum, int nb) {
  __shared__ int wsum[4];
  __shared__ int carry_s;
  const int t = threadIdx.x, lane = t & 63, wid = t >> 6;
  if (t == 0) carry_s = 0;
  __syncthreads();
  for (int base = 0; base < nb; base += 256) {
    int i = base + t;
    int v = (i < nb) ? bsum[i] : 0;
    int inc = v;
#pragma unroll
    for (int o = 1; o < 64; o <<= 1) { int x = __shfl_up(inc, o); if (lane >= o) inc += x; }
    if (lane == 63) wsum[wid] = inc;
    __syncthreads();
    int woff = 0;
    for (int w = 0; w < wid; w++) woff += wsum[w];
    int excl = carry_s + woff + inc - v;
    if (i < nb) bsum[i] = excl;
    __syncthreads();
    if (t == 0) carry_s += wsum[0] + wsum[1] + wsum[2] + wsum[3];
    __syncthreads();
  }
}

__global__ __launch_bounds__(256) void scan_k3(const int* __restrict__ deg,
    const int* __restrict__ bsum, int* __restrict__ rowstart,
    int* __restrict__ cur, int N) {
  __shared__ int wsum[4];
  const int t = threadIdx.x, lane = t & 63, wid = t >> 6;
  int i = blockIdx.x * 256 + t;
  int v = (i < N) ? deg[i] : 0;
  int inc = v;
#pragma unroll
  for (int o = 1; o < 64; o <<= 1) { int x = __shfl_up(inc, o); if (lane >= o) inc += x; }
  if (lane == 63) wsum[wid] = inc;
  __syncthreads();
  int woff = 0;
  for (int w = 0; w < wid; w++) woff += wsum[w];
  int excl = bsum[blockIdx.x] + woff + inc - v;
  if (i < N) { rowstart[i] = excl; cur[i] = excl; }
  if (i == N - 1) rowstart[N] = excl + v;
}

__global__ __launch_bounds__(256) void scatter_csr(const int* __restrict__ ei,
    int* __restrict__ cur, int* __restrict__ csr_src, int E) {
  int e = blockIdx.x * 256 + threadIdx.x;
  if (e >= E) return;
  int s = ei[e], d = ei[E + e];
  int pos = atomicAdd(&cur[d], 1);
  csr_src[pos] = s;
}

// ---------------- GEMM1 fused: h1 = x @ w1t^T, BM=128 x BN=256, 8 waves ----------------
// A (fp32 x) staged ONCE per block (read once globally); waves 0-3 cols 0-127, waves 4-7 cols 128-255.
// Per-wave K-loop identical to the proven 4-wave kernel (acc[4][4], 16 MFMA/iter). r6-measured best.
__global__ __launch_bounds__(512) void gemm1_fused(const float* __restrict__ A,
    const __bf16* __restrict__ Bt, __bf16* __restrict__ C,
    const float* __restrict__ asw, const float* __restrict__ adw,
    float* __restrict__ a_src, float* __restrict__ a_dst, int M) {
  __shared__ __bf16 Al[128 * 32];
  __shared__ __bf16 Bl[256 * 32];
  const int tid = threadIdx.x, lane = tid & 63, wave = tid >> 6;  // wave 0..7
  const int lm = lane & 15, q = lane >> 4;
  const int wr = ((wave >> 1) & 1) * 64;                 // row half: 0 or 64
  const int cb = (wave >> 2) * 128 + (wave & 1) * 64;    // col block: 0,64,128,192
  const int bm = blockIdx.x * 128;
  const int srow = tid >> 2, skc = (tid & 3) * 8;        // srow 0..127

  f32x4 acc[4][4];
#pragma unroll
  for (int i = 0; i < 4; i++)
#pragma unroll
    for (int j = 0; j < 4; j++) acc[i][j] = (f32x4){0.f, 0.f, 0.f, 0.f};

  const int ra = min(bm + srow, M - 1);

  float4 a0, a1;
  bf16x8 vb0, vb1;
  a0  = *(const float4*)(A + (size_t)ra * 512 + skc);
  a1  = *(const float4*)(A + (size_t)ra * 512 + skc + 4);
  vb0 = *(const bf16x8*)(Bt + (size_t)srow * 512 + skc);
  vb1 = *(const bf16x8*)(Bt + (size_t)(srow + 128) * 512 + skc);

  for (int kk = 0; kk < 16; kk++) {
    __syncthreads();
    *(bf16x8*)(Al + srow * 32 + skc)         = cvt8(a0, a1);
    *(bf16x8*)(Bl + srow * 32 + skc)         = vb0;
    *(bf16x8*)(Bl + (srow + 128) * 32 + skc) = vb1;
    __syncthreads();
    if (kk + 1 < 16) {
      const int k0 = (kk + 1) * 32;
      a0  = *(const float4*)(A + (size_t)ra * 512 + k0 + skc);
      a1  = *(const float4*)(A + (size_t)ra * 512 + k0 + skc + 4);
      vb0 = *(const bf16x8*)(Bt + (size_t)srow * 512 + k0 + skc);
      vb1 = *(const bf16x8*)(Bt + (size_t)(srow + 128) * 512 + k0 + skc);
    }
    bf16x8 af[4], bfr[4];
#pragma unroll
    for (int mi = 0; mi < 4; mi++)
      af[mi] = *(const bf16x8*)(Al + (wr + mi * 16 + lm) * 32 + q * 8);
#pragma unroll
    for (int ni = 0; ni < 4; ni++)
      bfr[ni] = *(const bf16x8*)(Bl + (cb + ni * 16 + lm) * 32 + q * 8);
#pragma unroll
    for (int mi = 0; mi < 4; mi++)
#pragma unroll
      for (int ni = 0; ni < 4; ni++)
        acc[mi][ni] = __builtin_amdgcn_mfma_f32_16x16x32_bf16(af[mi], bfr[ni], acc[mi][ni], 0, 0, 0);
  }

  // store h1 (bf16)
#pragma unroll
  for (int mi = 0; mi < 4; mi++) {
#pragma unroll
    for (int ni = 0; ni < 4; ni++) {
      const int col = cb + ni * 16 + lm;
#pragma unroll
      for (int r = 0; r < 4; r++) {
        const int row = bm + wr + mi * 16 + q * 4 + r;
        if (row < M) C[(size_t)row * C1 + col] = (__bf16)acc[mi][ni][r];
      }
    }
  }

  // fused scores from fp32 acc: this wave covers heads h0, h0+1 (cols cb .. cb+63)
  {
    const int h0 = cb >> 5;
    float ws[4], wd[4];
#pragma unroll
    for (int ni = 0; ni < 4; ni++) {
      ws[ni] = asw[cb + ni * 16 + lm];
      wd[ni] = adw[cb + ni * 16 + lm];
    }
#pragma unroll
    for (int mi = 0; mi < 4; mi++) {
#pragma unroll
      for (int r = 0; r < 4; r++) {
        float ps0 = acc[mi][0][r] * ws[0] + acc[mi][1][r] * ws[1];
        float ps1 = acc[mi][2][r] * ws[2] + acc[mi][3][r] * ws[3];
        float pd0 = acc[mi][0][r] * wd[0] + acc[mi][1][r] * wd[1];
        float pd1 = acc[mi][2][r] * wd[2] + acc[mi][3][r] * wd[3];
#pragma unroll
        for (int o = 1; o <= 8; o <<= 1) {
          ps0 += __shfl_xor(ps0, o); ps1 += __shfl_xor(ps1, o);
          pd0 += __shfl_xor(pd0, o); pd1 += __shfl_xor(pd1, o);
        }
        if (lm == 0) {
          const int row = bm + wr + mi * 16 + q * 4 + r;
          if (row < M) {
            a_src[(size_t)row * 8 + h0]     = ps0;
            a_src[(size_t)row * 8 + h0 + 1] = ps1;
            a_dst[(size_t)row * 8 + h0]     = pd0;
            a_dst[(size_t)row * 8 + h0 + 1] = pd1;
          }
        }
      }
    }
  }
}

// ---------------- GEMM2 fused: h2b = o1 @ w2t^T (bf16 out) + att scores 2 ----------------
__global__ __launch_bounds__(256) void gemm2_fused(const __bf16* __restrict__ A,
    const __bf16* __restrict__ Bt, __bf16* __restrict__ C,
    const float* __restrict__ asw, const float* __restrict__ adw,
    float* __restrict__ a_src, float* __restrict__ a_dst, int M) {
  __shared__ __bf16 Al[128 * 32];
  __shared__ __bf16 Bl[64 * 32];
  __shared__ float sred[128][2][2];
  const int tid = threadIdx.x, lane = tid & 63, wave = tid >> 6;
  const int lm = lane & 15, q = lane >> 4;
  const int wr = (wave >> 1) * 64, wc = (wave & 1) * 32;
  const int bm = blockIdx.x * 128;
  const int srow = tid >> 2, skc = (tid & 3) * 8;

  f32x4 acc[4][2];
#pragma unroll
  for (int i = 0; i < 4; i++)
#pragma unroll
    for (int j = 0; j < 2; j++) acc[i][j] = (f32x4){0.f, 0.f, 0.f, 0.f};

  const int ra0 = min(bm + srow, M - 1);
  const int ra1 = min(bm + srow + 64, M - 1);

  bf16x8 va0, va1, vb;
  va0 = *(const bf16x8*)(A + (size_t)ra0 * C1 + skc);
  va1 = *(const bf16x8*)(A + (size_t)ra1 * C1 + skc);
  vb  = *(const bf16x8*)(Bt + (size_t)srow * C1 + skc);

  for (int kk = 0; kk < 8; kk++) {
    __syncthreads();
    *(bf16x8*)(Al + srow * 32 + skc)        = va0;
    *(bf16x8*)(Al + (srow + 64) * 32 + skc) = va1;
    *(bf16x8*)(Bl + srow * 32 + skc)        = vb;
    __syncthreads();
    if (kk + 1 < 8) {
      const int k0 = (kk + 1) * 32;
      va0 = *(const bf16x8*)(A + (size_t)ra0 * C1 + k0 + skc);
      va1 = *(const bf16x8*)(A + (size_t)ra1 * C1 + k0 + skc);
      vb  = *(const bf16x8*)(Bt + (size_t)srow * C1 + k0 + skc);
    }
    bf16x8 af[4], bfr[2];
#pragma unroll
    for (int mi = 0; mi < 4; mi++)
      af[mi] = *(const bf16x8*)(Al + (wr + mi * 16 + lm) * 32 + q * 8);
#pragma unroll
    for (int ni = 0; ni < 2; ni++)
      bfr[ni] = *(const bf16x8*)(Bl + (wc + ni * 16 + lm) * 32 + q * 8);
#pragma unroll
    for (int mi = 0; mi < 4; mi++)
#pragma unroll
      for (int ni = 0; ni < 2; ni++)
        acc[mi][ni] = __builtin_amdgcn_mfma_f32_16x16x32_bf16(af[mi], bfr[ni], acc[mi][ni], 0, 0, 0);
  }

  float ws[2], wd[2];
#pragma unroll
  for (int ni = 0; ni < 2; ni++) {
    ws[ni] = asw[wc + ni * 16 + lm];
    wd[ni] = adw[wc + ni * 16 + lm];
  }
#pragma unroll
  for (int mi = 0; mi < 4; mi++) {
#pragma unroll
    for (int ni = 0; ni < 2; ni++) {
      const int col = wc + ni * 16 + lm;
#pragma unroll
      for (int r = 0; r < 4; r++) {
        const int row = bm + wr + mi * 16 + q * 4 + r;
        if (row < M) C[(size_t)row * CLS + col] = (__bf16)acc[mi][ni][r];
      }
    }
#pragma unroll
    for (int r = 0; r < 4; r++) {
      float ps = acc[mi][0][r] * ws[0] + acc[mi][1][r] * ws[1];
      float pd = acc[mi][0][r] * wd[0] + acc[mi][1][r] * wd[1];
#pragma unroll
      for (int o = 1; o <= 8; o <<= 1) { ps += __shfl_xor(ps, o); pd += __shfl_xor(pd, o); }
      if (lm == 0) {
        const int rl = wr + mi * 16 + q * 4 + r;
        sred[rl][wave & 1][0] = ps;
        sred[rl][wave & 1][1] = pd;
      }
    }
  }
  __syncthreads();
  if (tid < 128) {
    const int row = bm + tid;
    if (row < M) {
      a_src[row] = sred[tid][0][0] + sred[tid][1][0];
      a_dst[row] = sred[tid][0][1] + sred[tid][1][1];
    }
  }
}

// ---------------- layer-1 gather (r0-proven exact: ~76.7µs, VGPR 36, occ 61%) ----------------
__global__ __launch_bounds__(256) void gather1(const int* __restrict__ rowstart,
    const int* __restrict__ csr_src, const __bf16* __restrict__ h1,
    const float* __restrict__ as1, const float* __restrict__ ad1,
    const float* __restrict__ b1, __bf16* __restrict__ o1, int N) {
  const int t = threadIdx.x;
  const int d = blockIdx.x * 4 + (t >> 6);
  if (d >= N) return;
  const int lane = t & 63;
  const int e8 = lane >> 3, hh = lane & 7;
  const int r0 = rowstart[d];
  const int deg = rowstart[d + 1] - r0;

  const float addh = ad1[(size_t)d * 8 + hh];
  const float self_sc = leaky(as1[(size_t)d * 8 + hh] + addh);

  int   se[8];
  float sc[8];
#pragma unroll
  for (int ch = 0; ch < 8; ch++) {
    const int j = ch * 8 + e8;
    se[ch] = 0; sc[ch] = -3.4e38f;
    if (j < deg) {
      int s = csr_src[r0 + j];
      se[ch] = s;
      sc[ch] = leaky(as1[(size_t)s * 8 + hh] + addh);
    }
  }
  float mx = -3.4e38f;
#pragma unroll
  for (int ch = 0; ch < 8; ch++) mx = fmaxf(mx, sc[ch]);
  for (int j0 = 64; j0 < deg; j0 += 8) {
    int j = j0 + e8;
    if (j < deg) {
      int s = csr_src[r0 + j];
      mx = fmaxf(mx, leaky(as1[(size_t)s * 8 + hh] + addh));
    }
  }
  mx = fmaxf(mx, __shfl_xor(mx, 8));
  mx = fmaxf(mx, __shfl_xor(mx, 16));
  mx = fmaxf(mx, __shfl_xor(mx, 32));
  mx = fmaxf(mx, self_sc);

  float sum = 0.f;
#pragma unroll
  for (int ch = 0; ch < 8; ch++)
    if (ch * 8 + e8 < deg) sum += __expf(sc[ch] - mx);
  for (int j0 = 64; j0 < deg; j0 += 8) {
    int j = j0 + e8;
    if (j < deg) {
      int s = csr_src[r0 + j];
      sum += __expf(leaky(as1[(size_t)s * 8 + hh] + addh) - mx);
    }
  }
  sum += __shfl_xor(sum, 8);
  sum += __shfl_xor(sum, 16);
  sum += __shfl_xor(sum, 32);
  sum += __expf(self_sc - mx);
  const float inv = 1.f / (sum + EPS);

  float al[8];
#pragma unroll
  for (int ch = 0; ch < 8; ch++) al[ch] = __expf(sc[ch] - mx) * inv;
  const float al_self_byhh = __expf(self_sc - mx) * inv;

  const int p = lane >> 5, g = lane & 31, hg = g >> 2;
  float acc[8];
#pragma unroll
  for (int i = 0; i < 8; i++) acc[i] = 0.f;

#pragma unroll
  for (int it = 0; it < 32; it++) {
    if (it * 2 < deg) {
      const int   j   = it * 2 + p;
      const int   s_j = __shfl(se[it >> 2], (j & 7) * 8);
      const float a_j = __shfl(al[it >> 2], (j & 7) * 8 + hg);
      bf16x8 x = *(const bf16x8*)(h1 + (size_t)s_j * C1 + g * 8);
#pragma unroll
      for (int i = 0; i < 8; i++) acc[i] += a_j * (float)x[i];
    }
  }
  for (int j0 = 64; j0 < deg; j0 += 8) {
    int j = j0 + e8;
    int se2 = 0; float al2 = 0.f;
    if (j < deg) { se2 = csr_src[r0 + j]; al2 = __expf(leaky(as1[(size_t)se2 * 8 + hh] + addh) - mx) * inv; }
#pragma unroll
    for (int it = 0; it < 4; it++) {
      if (j0 + it * 2 < deg) {
        const int   jj  = it * 2 + p;
        const int   s_j = __shfl(se2, jj * 8);
        const float a_j = __shfl(al2, jj * 8 + hg);
        bf16x8 x = *(const bf16x8*)(h1 + (size_t)s_j * C1 + g * 8);
#pragma unroll
        for (int i = 0; i < 8; i++) acc[i] += a_j * (float)x[i];
      }
    }
  }
#pragma unroll
  for (int i = 0; i < 8; i++) acc[i] += __shfl_xor(acc[i], 32);

  const float a_selfh = __shfl(al_self_byhh, hg);
  if (lane < 32) {
    bf16x8 xs = *(const bf16x8*)(h1 + (size_t)d * C1 + g * 8);
    const float4 b4a = *(const float4*)(b1 + g * 8);
    const float4 b4b = *(const float4*)(b1 + g * 8 + 4);
    bf16x8 o;
    o[0] = (__bf16)fmaxf(acc[0] + a_selfh * (float)xs[0] + b4a.x, 0.f);
    o[1] = (__bf16)fmaxf(acc[1] + a_selfh * (float)xs[1] + b4a.y, 0.f);
    o[2] = (__bf16)fmaxf(acc[2] + a_selfh * (float)xs[2] + b4a.z, 0.f);
    o[3] = (__bf16)fmaxf(acc[3] + a_selfh * (float)xs[3] + b4a.w, 0.f);
    o[4] = (__bf16)fmaxf(acc[4] + a_selfh * (float)xs[4] + b4b.x, 0.f);
    o[5] = (__bf16)fmaxf(acc[5] + a_selfh * (float)xs[5] + b4b.y, 0.f);
    o[6] = (__bf16)fmaxf(acc[6] + a_selfh * (float)xs[6] + b4b.z, 0.f);
    o[7] = (__bf16)fmaxf(acc[7] + a_selfh * (float)xs[7] + b4b.w, 0.f);
    *(bf16x8*)(o1 + (size_t)d * C1 + g * 8) = o;
  }
}

// ---------------- layer-2 gather: no-max softmax + 2-deep pipeline + log_softmax ----------------
__global__ __launch_bounds__(256) void gather2(const int* __restrict__ rowstart,
    const int* __restrict__ csr_src, const __bf16* __restrict__ h2b,
    const float* __restrict__ as2, const float* __restrict__ ad2,
    const float* __restrict__ b2, float* __restrict__ out, int N) {
  const int t = threadIdx.x, lane = t & 63;
  const int d = blockIdx.x * 4 + (t >> 6);
  if (d >= N) return;
  const int r0 = rowstart[d], deg = rowstart[d + 1] - r0;
  const float addd = ad2[d];
  const float self_e = __expf(leaky(as2[d] + addd));

  int se = 0; float ex = 0.f;
  if (lane < deg) { se = csr_src[r0 + lane]; ex = __expf(leaky(as2[se] + addd)); }
  float sum = ex;
  for (int j0 = 64; j0 < deg; j0 += 64) {
    int j = j0 + lane;
    if (j < deg) sum += __expf(leaky(as2[csr_src[r0 + j]] + addd));
  }
#pragma unroll
  for (int o = 1; o < 64; o <<= 1) sum += __shfl_xor(sum, o);
  sum += self_e;
  const float inv = 1.f / (sum + EPS);
  const float alpha = ex * inv;          // 0 for padded edges
  const float al_self = self_e * inv;

  const int e8 = lane >> 3, c8 = lane & 7;
  float acc[8];
#pragma unroll
  for (int i = 0; i < 8; i++) acc[i] = 0.f;

  // 16 edges per guarded group, 2 gathers in flight
#pragma unroll
  for (int itg = 0; itg < 8; itg += 2) {
    if (itg * 8 < deg) {
      const int   sa = __shfl(se, itg * 8 + e8);
      const int   sb = __shfl(se, itg * 8 + 8 + e8);
      const float aa = __shfl(alpha, itg * 8 + e8);
      const float ab = __shfl(alpha, itg * 8 + 8 + e8);
      bf16x8 xa = *(const bf16x8*)(h2b + ((uint32_t)sa * 64u + (uint32_t)(c8 * 8)));
      bf16x8 xb = *(const bf16x8*)(h2b + ((uint32_t)sb * 64u + (uint32_t)(c8 * 8)));
#pragma unroll
      for (int i = 0; i < 8; i++) acc[i] += aa * (float)xa[i];
#pragma unroll
      for (int i = 0; i < 8; i++) acc[i] += ab * (float)xb[i];
    }
  }
  for (int j0 = 64; j0 < deg; j0 += 64) {
    int j = j0 + lane;
    int se2 = 0; float al2 = 0.f;
    if (j < deg) { se2 = csr_src[r0 + j]; al2 = __expf(leaky(as2[se2] + addd)) * inv; }
#pragma unroll
    for (int it = 0; it < 8; it++) {
      if (j0 + it * 8 < deg) {
        const int   jj  = it * 8 + e8;
        const int   s_j = __shfl(se2, jj);
        const float a_j = __shfl(al2, jj);
        bf16x8 x = *(const bf16x8*)(h2b + ((uint32_t)s_j * 64u + (uint32_t)(c8 * 8)));
#pragma unroll
        for (int i = 0; i < 8; i++) acc[i] += a_j * (float)x[i];
      }
    }
  }
#pragma unroll
  for (int i = 0; i < 8; i++) {
    acc[i] += __shfl_xor(acc[i], 8);
    acc[i] += __shfl_xor(acc[i], 16);
    acc[i] += __shfl_xor(acc[i], 32);
  }

  bf16x8 xs = *(const bf16x8*)(h2b + ((uint32_t)d * 64u + (uint32_t)(c8 * 8)));
  const float4 bba = *(const float4*)(b2 + c8 * 8);
  const float4 bbb = *(const float4*)(b2 + c8 * 8 + 4);
  float v[8];
  v[0] = acc[0] + al_self * (float)xs[0] + bba.x;
  v[1] = acc[1] + al_self * (float)xs[1] + bba.y;
  v[2] = acc[2] + al_self * (float)xs[2] + bba.z;
  v[3] = acc[3] + al_self * (float)xs[3] + bba.w;
  v[4] = acc[4] + al_self * (float)xs[4] + bbb.x;
  v[5] = acc[5] + al_self * (float)xs[5] + bbb.y;
  v[6] = acc[6] + al_self * (float)xs[6] + bbb.z;
  v[7] = acc[7] + al_self * (float)xs[7] + bbb.w;
  float m2 = v[0];
#pragma unroll
  for (int i = 1; i < 8; i++) m2 = fmaxf(m2, v[i]);
  m2 = fmaxf(m2, __shfl_xor(m2, 1));
  m2 = fmaxf(m2, __shfl_xor(m2, 2));
  m2 = fmaxf(m2, __shfl_xor(m2, 4));
  float sm = 0.f;
#pragma unroll
  for (int i = 0; i < 8; i++) sm += __expf(v[i] - m2);
  sm += __shfl_xor(sm, 1);
  sm += __shfl_xor(sm, 2);
  sm += __shfl_xor(sm, 4);
  const float lg = m2 + __logf(sm);
  if (lane < 8) {
    float4 o0, o1v;
    o0.x  = v[0] - lg; o0.y  = v[1] - lg; o0.z  = v[2] - lg; o0.w  = v[3] - lg;
    o1v.x = v[4] - lg; o1v.y = v[5] - lg; o1v.z = v[6] - lg; o1v.w = v[7] - lg;
    *(float4*)(out + (size_t)d * CLS + c8 * 8)     = o0;
    *(float4*)(out + (size_t)d * CLS + c8 * 8 + 4) = o1v;
  }
}

extern "C" void kernel_launch(void* const* d_in, const int* in_sizes, int n_in,
                              void* d_out, int out_size, void* d_ws, size_t ws_size,
                              hipStream_t stream) {
  const float* x        = (const float*)d_in[0];
  const int*   ei       = (const int*)d_in[1];
  const float* W1       = (const float*)d_in[2];
  const float* att_src1 = (const float*)d_in[3];
  const float* att_dst1 = (const float*)d_in[4];
  const float* b1       = (const float*)d_in[5];
  const float* W2       = (const float*)d_in[6];
  const float* att_src2 = (const float*)d_in[7];
  const float* att_dst2 = (const float*)d_in[8];
  const float* b2       = (const float*)d_in[9];
  float* out = (float*)d_out;

  const int N  = in_sizes[0] / F_IN;   // 50000
  const int E  = in_sizes[1] / 2;      // 800000
  const int NB = (N + 255) / 256;

  char* ws = (char*)d_ws;
  size_t off = 0;
  auto alloc = [&](size_t bytes) -> void* {
    void* p = ws + off;
    off += (bytes + 255) & ~(size_t)255;
    return p;
  };
  __bf16* h1  = (__bf16*)alloc((size_t)N * C1 * 2);
  __bf16* o1  = (__bf16*)alloc((size_t)N * C1 * 2);
  float*  as1 = (float*)alloc((size_t)N * HEADS * 4);
  float*  ad1 = (float*)alloc((size_t)N * HEADS * 4);
  __bf16* h2b = (__bf16*)alloc((size_t)N * CLS * 2);
  float*  as2 = (float*)alloc((size_t)N * 4);
  float*  ad2 = (float*)alloc((size_t)N * 4);
  int* deg      = (int*)alloc((size_t)N * 4);
  int* rowstart = (int*)alloc((size_t)(N + 1) * 4);
  int* cur      = (int*)alloc((size_t)N * 4);
  int* csr_src  = (int*)alloc((size_t)E * 4);
  int* bsum     = (int*)alloc((size_t)NB * 4);
  __bf16* w1t = (__bf16*)alloc((size_t)C1 * F_IN * 2);
  __bf16* w2t = (__bf16*)alloc((size_t)CLS * C1 * 2);

  // ---- prep: weight casts + degree histogram ----
  hipMemsetAsync(deg, 0, (size_t)N * 4, stream);
  prep<<<72 + (E + 255) / 256, 256, 0, stream>>>(W1, W2, ei, w1t, w2t, deg, E);

  // ---- parallel scan -> rowstart, cur ----
  scan_k1<<<NB, 256, 0, stream>>>(deg, bsum, N);
  scan_k2<<<1, 256, 0, stream>>>(bsum, NB);
  scan_k3<<<NB, 256, 0, stream>>>(deg, bsum, rowstart, cur, N);
  scatter_csr<<<(E + 255) / 256, 256, 0, stream>>>(ei, cur, csr_src, E);

  // ---- layer 1: GEMM (BM=128 x BN=256, 8 waves, A read once) + scores fused ----
  gemm1_fused<<<(N + 127) / 128, 512, 0, stream>>>(x, w1t, h1, att_src1, att_dst1, as1, ad1, N);
  gather1<<<(N + 3) / 4, 256, 0, stream>>>(rowstart, csr_src, h1, as1, ad1, b1, o1, N);

  // ---- layer 2: GEMM + scores fused ----
  gemm2_fused<<<(N + 127) / 128, 256, 0, stream>>>(o1, w2t, h2b, att_src2, att_dst2, as2, ad2, N);
  gather2<<<(N + 3) / 4, 256, 0, stream>>>(rowstart, csr_src, h2b, as2, ad2, b2, out, N);
}